// Round 4
// baseline (2522.779 us; speedup 1.0000x reference)
//
#include <hip/hip_runtime.h>
#include <math.h>

#define N_NODES 100000
#define N_IN 512
#define N_H 256
#define N_OUT 64
#define KHOP 10
#define EPS_BN 1e-5f
#define INV_TEMP (1.0f/1.5f)
#define TILE_W 25000          // column-tile width: 25000 nodes * 128B z-row = 3.2MB (L2-resident)

using half8  = __attribute__((ext_vector_type(8))) _Float16;
using half4  = __attribute__((ext_vector_type(4))) _Float16;
using floatx4 = __attribute__((ext_vector_type(4))) float;

struct ZPtrs { const _Float16* p[KHOP]; };

// ---------------- CSR build (tiled: segments per (row, col-tile)) ----------------

__global__ void init_kernel(int* __restrict__ cnt4, float* __restrict__ sums, int n4) {
    int i = blockIdx.x * blockDim.x + threadIdx.x;
    if (i < n4) cnt4[i] = 0;
    if (i < 2 * N_H) sums[i] = 0.f;
}

// Pre-pass (grid union): edge-rank atomics (per (row,tile) segment) + weight transposes.
// NOTE: deliberately NO bulk streaming here — co-scheduling streams under the
// atomic-RMW wall contended (R1: 205us vs 128us atomic-only).
__global__ __launch_bounds__(256) void fused_pre_kernel(
    const int* __restrict__ ei, int* __restrict__ cnt4, unsigned short* __restrict__ pos,
    const float* __restrict__ w1, _Float16* __restrict__ w1T,
    const float* __restrict__ w2, _Float16* __restrict__ w2T,
    const float* __restrict__ w3, _Float16* __restrict__ w3T,
    const float* __restrict__ w4, _Float16* __restrict__ w4T,
    int E, int nbE) {
    int bid = blockIdx.x;
    int t = threadIdx.x;
    if (bid < nbE) {
        int i = bid * 256 + t;
        if (i < E) {
            int r = ei[i];
            int c = ei[E + i];
            pos[i] = (unsigned short)atomicAdd(&cnt4[(r << 2) + c / TILE_W], 1);
        }
        return;
    }
    bid -= nbE;
    if (bid < 512) {            // w1: [512][256] -> w1T[n*512+k]
        int i = bid * 256 + t;
        int k = i >> 8, n = i & 255;
        w1T[(size_t)n * 512 + k] = (_Float16)w1[i];
        return;
    }
    bid -= 512;
    if (bid < 256) {            // w2: [256][256]
        int i = bid * 256 + t;
        int k = i >> 8, n = i & 255;
        w2T[(size_t)n * 256 + k] = (_Float16)w2[i];
        return;
    }
    bid -= 256;
    if (bid < 256) {            // w3: [256][256]
        int i = bid * 256 + t;
        int k = i >> 8, n = i & 255;
        w3T[(size_t)n * 256 + k] = (_Float16)w3[i];
        return;
    }
    bid -= 256;
    {                           // w4: [256][64]
        int i = bid * 256 + t;
        int k = i >> 6, n = i & 63;
        w4T[(size_t)n * 256 + k] = (_Float16)w4[i];
    }
}

// scan over 4N (row,tile) counts; self-loop (+1) added at tile (r / TILE_W).
// block = 256 threads x 4 elems = 1024 per block.
__global__ void scan1_kernel(const int* __restrict__ cnt4, int* __restrict__ excl,
                             int* __restrict__ bsum, int n4) {
    __shared__ int sd[256];
    int t = threadIdx.x;
    int base = blockIdx.x * 1024 + t * 4;
    int v0 = 0, v1 = 0, v2 = 0, v3 = 0;
    if (base + 0 < n4) { int g = base + 0; v0 = cnt4[g] + (((g & 3) == ((g >> 2) / TILE_W)) ? 1 : 0); }
    if (base + 1 < n4) { int g = base + 1; v1 = cnt4[g] + (((g & 3) == ((g >> 2) / TILE_W)) ? 1 : 0); }
    if (base + 2 < n4) { int g = base + 2; v2 = cnt4[g] + (((g & 3) == ((g >> 2) / TILE_W)) ? 1 : 0); }
    if (base + 3 < n4) { int g = base + 3; v3 = cnt4[g] + (((g & 3) == ((g >> 2) / TILE_W)) ? 1 : 0); }
    int tot = v0 + v1 + v2 + v3;
    sd[t] = tot;
    __syncthreads();
    for (int off = 1; off < 256; off <<= 1) {
        int x = (t >= off) ? sd[t - off] : 0;
        __syncthreads();
        sd[t] += x;
        __syncthreads();
    }
    int run = sd[t] - tot;   // exclusive
    if (t == 255) bsum[blockIdx.x] = sd[t];
    if (base + 0 < n4) excl[base + 0] = run; run += v0;
    if (base + 1 < n4) excl[base + 1] = run; run += v1;
    if (base + 2 < n4) excl[base + 2] = run; run += v2;
    if (base + 3 < n4) excl[base + 3] = run;
}

__global__ void scan2_kernel(int* __restrict__ bsum, int nb) {
    __shared__ int sd[512];
    int t = threadIdx.x;
    int v = (t < nb) ? bsum[t] : 0;
    sd[t] = v;
    __syncthreads();
    for (int off = 1; off < 512; off <<= 1) {
        int x = (t >= off) ? sd[t - off] : 0;
        __syncthreads();
        sd[t] += x;
        __syncthreads();
    }
    if (t < nb) bsum[t] = sd[t] - v;   // exclusive
}

// finalize rp4, per-node scalars, and write self-loop columns (at end of own tile segment).
__global__ void scan3_kernel(int* __restrict__ rp4, const int* __restrict__ bsum,
                             const int* __restrict__ cnt4, float* __restrict__ dinv,
                             float* __restrict__ dinv2, float* __restrict__ sqd,
                             int* __restrict__ colv, int n4, int total) {
    int g = blockIdx.x * blockDim.x + threadIdx.x;
    if (g < n4) {
        int rpf = rp4[g] + bsum[g >> 10];
        rp4[g] = rpf;
        int r = g >> 2, t = g & 3;
        int cv = cnt4[g];
        if (t == r / TILE_W) colv[rpf + cv] = r;   // self loop slot
        if (t == 0) {
            int4 c4 = *reinterpret_cast<const int4*>(&cnt4[g]);
            float d = (float)(c4.x + c4.y + c4.z + c4.w + 1);
            dinv[r]  = rsqrtf(d);
            dinv2[r] = 1.0f / d;
            sqd[r]   = sqrtf(d);
        }
    }
    if (g == 0) rp4[n4] = total;
}

// bucketed fill, NO atomics: slot from pos[] (rank within (row,tile) segment).
// Only rows in [r0, r1) handled per pass -> scatter window ~3.4 MB (L2-resident).
__global__ void fill_kernel(const int* __restrict__ ei, const unsigned short* __restrict__ pos,
                            const int* __restrict__ rp4,
                            int* __restrict__ colv, int E, int r0, int r1) {
    int i = blockIdx.x * blockDim.x + threadIdx.x;
    if (i >= E) return;
    int r = ei[i];
    if (r < r0 || r >= r1) return;
    int c = ei[E + i];
    colv[rp4[(r << 2) + c / TILE_W] + pos[i]] = c;
}

// ---------------- MFMA GEMM: C = A * BT^T + bias, with fused A-prologue ----------------
// BM=128, BN in {128, 64}. 256 threads = 4 waves in 2x2; each wave 4 x WTN tiles of
// 16x16, MFMA 16x16x32 f16.  (R2 lesson: BN=256/acc[4][8] caps occupancy at 3
// waves/SIMD -> latency-bound, 227us.  Keep BN=128/acc[4][4].)
// AMODE: 0 = A is f16; 1 = A is f32 (convert while staging);
//        2 = A is f16 pre-BN (apply ab-scale/shift + GELU while staging);
//        3 = like 2 plus residual add from res[].
// WRITE_X (gated to blockIdx.x==0): store staged activation to xout for later
// residual use.  STATS: fused column sum/sumsq.  WRITE_Z: z0 = dinv[row]*C (f16).
// NOT in-place: with grid.x=2, C rows would race with the other column-block's
// A-stage reads -> ping-pong buffers instead.
// LDS stride 40 halves (80B): frag ds_read_b128 bank-chunk = (5m+q) mod 8 -> conflict-free.

#define GELU(u) (0.5f * (u) * (1.f + erff((u) * 0.70710678118654752f)))

template<int KDIM, int NDIM, int BN, int AMODE, bool STATS, bool WRITE_X, bool WRITE_Z, typename CT>
__global__ __launch_bounds__(256) void gemm_mfma_kernel(
    const void* __restrict__ Araw, const _Float16* __restrict__ BT,
    const float* __restrict__ bias, CT* __restrict__ C, int M,
    float* __restrict__ sums, const float* __restrict__ ab,
    const _Float16* __restrict__ res, _Float16* __restrict__ xout,
    const float* __restrict__ dinv, _Float16* __restrict__ z0) {
    constexpr int BM = 128;
    constexpr int LDK = 40;
    constexpr int WTN = BN / 32;
    __shared__ _Float16 As[BM * LDK];
    __shared__ _Float16 Bs[BN * LDK];
    __shared__ float cs[BN];
    __shared__ float cq[BN];
    int t = threadIdx.x;
    int mbase = blockIdx.y * BM;
    int nbase = blockIdx.x * BN;
    int wv = t >> 6, lane = t & 63;
    int wm = (wv & 1) * 64;
    int wn = (wv >> 1) * (BN / 2);
    int q = lane >> 4;        // quad
    int fr = lane & 15;
    int sr = t >> 2;          // staging row 0..63
    int sc = (t & 3) * 8;     // staging k-offset (halves)
    bool xwrite = WRITE_X && (blockIdx.x == 0);

    floatx4 acc[4][WTN];
    for (int mt = 0; mt < 4; ++mt)
        for (int nt = 0; nt < WTN; ++nt)
            acc[mt][nt] = floatx4{0.f, 0.f, 0.f, 0.f};

    for (int k0 = 0; k0 < KDIM; k0 += 32) {
        int kc = k0 + sc;
        #pragma unroll
        for (int p = 0; p < 2; ++p) {
            int row = sr + p * 64;
            int grow = mbase + row;
            half8 v = {};
            if (grow < M) {
                if constexpr (AMODE == 0) {
                    v = *reinterpret_cast<const half8*>(
                        &((const _Float16*)Araw)[(size_t)grow * KDIM + kc]);
                } else if constexpr (AMODE == 1) {
                    const float* Af = (const float*)Araw + (size_t)grow * KDIM + kc;
                    float4 f0 = *reinterpret_cast<const float4*>(Af);
                    float4 f1 = *reinterpret_cast<const float4*>(Af + 4);
                    v[0] = (_Float16)f0.x; v[1] = (_Float16)f0.y;
                    v[2] = (_Float16)f0.z; v[3] = (_Float16)f0.w;
                    v[4] = (_Float16)f1.x; v[5] = (_Float16)f1.y;
                    v[6] = (_Float16)f1.z; v[7] = (_Float16)f1.w;
                } else {
                    half8 tv = *reinterpret_cast<const half8*>(
                        &((const _Float16*)Araw)[(size_t)grow * KDIM + kc]);
                    float4 a0 = *reinterpret_cast<const float4*>(&ab[kc]);
                    float4 a1 = *reinterpret_cast<const float4*>(&ab[kc + 4]);
                    float4 b0 = *reinterpret_cast<const float4*>(&ab[KDIM + kc]);
                    float4 b1 = *reinterpret_cast<const float4*>(&ab[KDIM + kc + 4]);
                    float u[8];
                    u[0] = a0.x * (float)tv[0] + b0.x;
                    u[1] = a0.y * (float)tv[1] + b0.y;
                    u[2] = a0.z * (float)tv[2] + b0.z;
                    u[3] = a0.w * (float)tv[3] + b0.w;
                    u[4] = a1.x * (float)tv[4] + b1.x;
                    u[5] = a1.y * (float)tv[5] + b1.y;
                    u[6] = a1.z * (float)tv[6] + b1.z;
                    u[7] = a1.w * (float)tv[7] + b1.w;
                    if constexpr (AMODE == 3) {
                        half8 rv = *reinterpret_cast<const half8*>(
                            &res[(size_t)grow * KDIM + kc]);
                        #pragma unroll
                        for (int j = 0; j < 8; ++j) u[j] += (float)rv[j];
                    }
                    #pragma unroll
                    for (int j = 0; j < 8; ++j) v[j] = (_Float16)GELU(u[j]);
                    if (xwrite)
                        *reinterpret_cast<half8*>(&xout[(size_t)grow * KDIM + kc]) = v;
                }
            }
            *reinterpret_cast<half8*>(&As[row * LDK + sc]) = v;
        }
        #pragma unroll
        for (int p = 0; p < BN / 64; ++p) {
            int row = sr + p * 64;
            half8 v = *reinterpret_cast<const half8*>(&BT[(size_t)(nbase + row) * KDIM + kc]);
            *reinterpret_cast<half8*>(&Bs[row * LDK + sc]) = v;
        }
        __syncthreads();
        half8 af[4], bf[WTN];
        #pragma unroll
        for (int mt = 0; mt < 4; ++mt)
            af[mt] = *reinterpret_cast<const half8*>(&As[(wm + mt * 16 + fr) * LDK + q * 8]);
        #pragma unroll
        for (int nt = 0; nt < WTN; ++nt)
            bf[nt] = *reinterpret_cast<const half8*>(&Bs[(wn + nt * 16 + fr) * LDK + q * 8]);
        #pragma unroll
        for (int mt = 0; mt < 4; ++mt)
            #pragma unroll
            for (int nt = 0; nt < WTN; ++nt)
                acc[mt][nt] = __builtin_amdgcn_mfma_f32_16x16x32_f16(af[mt], bf[nt], acc[mt][nt], 0, 0, 0);
        __syncthreads();
    }
    if constexpr (STATS) {
        if (t < BN) { cs[t] = 0.f; cq[t] = 0.f; }
        __syncthreads();
    }
    // epilogue: D layout col = lane&15, row = (lane>>4)*4 + r
    #pragma unroll
    for (int nt = 0; nt < WTN; ++nt) {
        int col = nbase + wn + nt * 16 + fr;
        float bv = bias[col];
        float s = 0.f, s2 = 0.f;
        #pragma unroll
        for (int mt = 0; mt < 4; ++mt) {
            #pragma unroll
            for (int rr = 0; rr < 4; ++rr) {
                int row = mbase + wm + mt * 16 + q * 4 + rr;
                if (row < M) {
                    float v = acc[mt][nt][rr] + bv;
                    C[(size_t)row * NDIM + col] = (CT)v;
                    if constexpr (STATS) { s += v; s2 += v * v; }
                    if constexpr (WRITE_Z)
                        z0[((size_t)row << 6) + col] = (_Float16)(dinv[row] * v);
                }
            }
        }
        if constexpr (STATS) {
            s  += __shfl_xor(s, 16);  s  += __shfl_xor(s, 32);
            s2 += __shfl_xor(s2, 16); s2 += __shfl_xor(s2, 32);
            if (q == 0) {
                atomicAdd(&cs[wn + nt * 16 + fr], s);
                atomicAdd(&cq[wn + nt * 16 + fr], s2);
            }
        }
    }
    if constexpr (STATS) {
        __syncthreads();
        if (t < BN) {
            atomicAdd(&sums[nbase + t], cs[t]);
            atomicAdd(&sums[N_H + nbase + t], cq[t]);
        }
    }
}

// ---------------- BatchNorm finalize (also re-zeroes sums for the next layer) ----------------

__global__ void finalize_stats_kernel(float* __restrict__ sums,
                                      const float* __restrict__ g, const float* __restrict__ be,
                                      float* __restrict__ ab, float invM) {
    int c = threadIdx.x;
    float s = sums[c], s2 = sums[N_H + c];
    float mean = s * invM;
    float var = s2 * invM - mean * mean;
    float a = g[c] * rsqrtf(var + EPS_BN);
    ab[c] = a;
    ab[N_H + c] = be[c] - mean * a;
    sums[c] = 0.f;
    sums[N_H + c] = 0.f;
}

// ---------------- Propagation (column-tiled SpMM) ----------------
// Per hop, 4 sub-passes over column tiles; sub-pass t gathers only from zin rows
// [t*TILE_W, (t+1)*TILE_W) = 3.2 MB -> L2-resident per XCD (vs 12.8 MB working set
// that spilled to L3 at ~5 TB/s effective).  f32 partials in zpart; single f16
// rounding at finalize (same numerics as before).
// PHASE 0: zpart = partial; PHASE 1: zpart += partial;
// PHASE 2: zout = (zpart + partial) * dinv2 (f16).
// 1024-thread blocks (16 rows, wave per row) keep workgroup count per hop at the
// pre-tiling level (launch-rate guard).

template<int PHASE>
__global__ __launch_bounds__(1024) void prop_tile_kernel(
    const _Float16* __restrict__ zin, float* __restrict__ zpart,
    _Float16* __restrict__ zout,
    const int* __restrict__ colv, const int* __restrict__ rp4,
    const float* __restrict__ dinv2, int n, int tile) {
    int r = (blockIdx.x << 4) + (threadIdx.x >> 6);
    if (r >= n) return;
    int lane = threadIdx.x & 63;
    int esub = lane >> 4;       // 0..3
    int fo = (lane & 15) << 2;  // feature offset 0..60
    int s = __builtin_amdgcn_readfirstlane(rp4[(r << 2) + tile]);
    int e = __builtin_amdgcn_readfirstlane(rp4[(r << 2) + tile + 1]);
    float a0 = 0.f, a1 = 0.f, a2 = 0.f, a3 = 0.f;
    int i = s;
    for (; i + 8 <= e; i += 8) {
        int c0 = colv[i + esub];
        int c1 = colv[i + 4 + esub];
        half4 v0 = *reinterpret_cast<const half4*>(&zin[((size_t)c0 << 6) + fo]);
        half4 v1 = *reinterpret_cast<const half4*>(&zin[((size_t)c1 << 6) + fo]);
        a0 += (float)v0.x + (float)v1.x;
        a1 += (float)v0.y + (float)v1.y;
        a2 += (float)v0.z + (float)v1.z;
        a3 += (float)v0.w + (float)v1.w;
    }
    for (; i + 4 <= e; i += 4) {
        int c = colv[i + esub];
        half4 v = *reinterpret_cast<const half4*>(&zin[((size_t)c << 6) + fo]);
        a0 += (float)v.x; a1 += (float)v.y; a2 += (float)v.z; a3 += (float)v.w;
    }
    if (esub < e - i) {
        int c = colv[i + esub];
        half4 v = *reinterpret_cast<const half4*>(&zin[((size_t)c << 6) + fo]);
        a0 += (float)v.x; a1 += (float)v.y; a2 += (float)v.z; a3 += (float)v.w;
    }
    a0 += __shfl_xor(a0, 16); a1 += __shfl_xor(a1, 16);
    a2 += __shfl_xor(a2, 16); a3 += __shfl_xor(a3, 16);
    a0 += __shfl_xor(a0, 32); a1 += __shfl_xor(a1, 32);
    a2 += __shfl_xor(a2, 32); a3 += __shfl_xor(a3, 32);
    if (lane < 16) {
        float4* zp = reinterpret_cast<float4*>(&zpart[((size_t)r << 6) + fo]);
        if constexpr (PHASE == 0) {
            *zp = float4{a0, a1, a2, a3};
        } else if constexpr (PHASE == 1) {
            float4 p = *zp;
            p.x += a0; p.y += a1; p.z += a2; p.w += a3;
            *zp = p;
        } else {
            float4 p = *zp;
            float d = dinv2[r];
            half4 o;
            o.x = (_Float16)((a0 + p.x) * d); o.y = (_Float16)((a1 + p.y) * d);
            o.z = (_Float16)((a2 + p.z) * d); o.w = (_Float16)((a3 + p.w) * d);
            *reinterpret_cast<half4*>(&zout[((size_t)r << 6) + fo]) = o;
        }
    }
}

// out = INV_TEMP * (alpha0 * h + sqrt(deg[r]) * sum_k alpha_k * z_k)
__global__ void prop_final_kernel(const float* __restrict__ h, ZPtrs zp,
                                  const float* __restrict__ sqd,
                                  const float* __restrict__ alpha,
                                  float* __restrict__ out, int total4) {
    int i = blockIdx.x * blockDim.x + threadIdx.x;
    if (i >= total4) return;
    int r = i >> 4;                       // (i*4)/64
    float4 hv = reinterpret_cast<const float4*>(h)[i];
    float s0 = 0.f, s1 = 0.f, s2 = 0.f, s3 = 0.f;
    #pragma unroll
    for (int k = 0; k < KHOP; ++k) {
        half4 z = reinterpret_cast<const half4*>(zp.p[k])[i];
        float ak = alpha[k + 1];
        s0 += ak * (float)z.x; s1 += ak * (float)z.y;
        s2 += ak * (float)z.z; s3 += ak * (float)z.w;
    }
    float sq = sqd[r];
    float a0 = alpha[0];
    float4 o;
    o.x = INV_TEMP * (a0 * hv.x + sq * s0);
    o.y = INV_TEMP * (a0 * hv.y + sq * s1);
    o.z = INV_TEMP * (a0 * hv.z + sq * s2);
    o.w = INV_TEMP * (a0 * hv.w + sq * s3);
    reinterpret_cast<float4*>(out)[i] = o;
}

// ---------------- Host ----------------

extern "C" void kernel_launch(void* const* d_in, const int* in_sizes, int n_in,
                              void* d_out, int out_size, void* d_ws, size_t ws_size,
                              hipStream_t stream) {
    const float* x    = (const float*)d_in[0];
    const int*   ei   = (const int*)d_in[1];
    const float* w1   = (const float*)d_in[2];
    const float* b1   = (const float*)d_in[3];
    const float* g1   = (const float*)d_in[4];
    const float* be1  = (const float*)d_in[5];
    const float* w2   = (const float*)d_in[6];
    const float* b2   = (const float*)d_in[7];
    const float* g2   = (const float*)d_in[8];
    const float* be2  = (const float*)d_in[9];
    const float* w3   = (const float*)d_in[10];
    const float* b3   = (const float*)d_in[11];
    const float* g3   = (const float*)d_in[12];
    const float* be3  = (const float*)d_in[13];
    const float* w4   = (const float*)d_in[14];
    const float* b4   = (const float*)d_in[15];
    const float* alpha= (const float*)d_in[16];
    float* out = (float*)d_out;

    const int N = in_sizes[0] / N_IN;     // 100000
    const int E = in_sizes[1] / 2;        // 3200000
    const int EN = E + N;
    const int N4 = N * 4;
    const size_t NZ = (size_t)N * N_OUT;  // elements per z buffer
    const int NT = (N + TILE_W - 1) / TILE_W;   // 4 column tiles

    char* ws = (char*)d_ws;
    size_t off = 0;
    auto alloc = [&](size_t bytes) -> void* {
        void* p = ws + off;
        off = (off + bytes + 255) & ~(size_t)255;
        return p;
    };
    int*   cnt4    = (int*)alloc((size_t)N4 * 4);         // per (row,tile) raw edge counts
    int*   rp4     = (int*)alloc((size_t)(N4 + 1) * 4);   // segment ptrs, row-major (r,t)
    float* dinv    = (float*)alloc((size_t)N * 4);
    float* dinv2   = (float*)alloc((size_t)N * 4);
    float* sqd     = (float*)alloc((size_t)N * 4);
    int*   colv    = (int*)alloc((size_t)EN * 4);
    unsigned short* pos = (unsigned short*)alloc((size_t)E * 2);
    int*   bsum    = (int*)alloc(512 * 4);
    float* sums    = (float*)alloc(2 * N_H * 4);
    float* ab      = (float*)alloc(2 * N_H * 4);
    _Float16* w1T  = (_Float16*)alloc((size_t)N_IN * N_H * 2);
    _Float16* w2T  = (_Float16*)alloc((size_t)N_H * N_H * 2);
    _Float16* w3T  = (_Float16*)alloc((size_t)N_H * N_H * 2);
    _Float16* w4T  = (_Float16*)alloc((size_t)N_H * N_OUT * 2);
    float* T       = (float*)alloc((size_t)N * N_H * 4);    // two f16 halves (ping-pong); reused as z1..z8
    _Float16* Ah0  = (_Float16*)alloc((size_t)N * N_H * 2); // x0
    _Float16* Ah1  = (_Float16*)alloc((size_t)N * N_H * 2); // x1; reused as z9,z10
    float* hbuf    = (float*)alloc((size_t)N * N_OUT * 4);
    _Float16* z0   = (_Float16*)alloc(NZ * 2);
    float* zpart   = (float*)alloc(NZ * 4);                 // f32 partial sums (tiled SpMM)

    _Float16* T16a = (_Float16*)T;
    _Float16* T16b = (_Float16*)T + (size_t)N * N_H;

    // z-buffer ring: z1..z8 live in T region (8*12.8MB), z9,z10 in Ah1
    _Float16* zk[KHOP + 1];
    zk[0] = z0;
    for (int k = 1; k <= 8; ++k) zk[k] = (_Float16*)T + (size_t)(k - 1) * NZ;
    zk[9]  = (_Float16*)Ah1;
    zk[10] = (_Float16*)Ah1 + NZ;

    const int TB = 256;
    int nbN4 = (N4 + TB - 1) / TB;
    int nbE  = (E + TB - 1) / TB;
    int nscan = (N4 + 1023) / 1024;

    // --- pre-pass: (row,tile) edge-rank atomics + weight transposes ---
    init_kernel<<<nbN4, TB, 0, stream>>>(cnt4, sums, N4);
    {
        int grid = nbE + 512 + 256 + 256 + 64;
        fused_pre_kernel<<<grid, TB, 0, stream>>>(ei, cnt4, pos,
                                                  w1, w1T, w2, w2T, w3, w3T, w4, w4T,
                                                  E, nbE);
    }

    // --- CSR scan + finalize (self loops written in scan3) ---
    scan1_kernel<<<nscan, TB, 0, stream>>>(cnt4, rp4, bsum, N4);
    scan2_kernel<<<1, 512, 0, stream>>>(bsum, nscan);
    scan3_kernel<<<nbN4, TB, 0, stream>>>(rp4, bsum, cnt4, dinv, dinv2, sqd, colv, N4, EN);

    // --- atomic-free bucketed fill ---
    {
        const int P = 4;
        int step = (N + P - 1) / P;
        for (int p = 0; p < P; ++p) {
            int r0 = p * step;
            int r1 = min(N, r0 + step);
            fill_kernel<<<nbE, TB, 0, stream>>>(ei, pos, rp4, colv, E, r0, r1);
        }
    }

    int mt = (N + 127) / 128;

    // --- layer 1: T1 = x(f32) @ w1 + b1 (A converted to f16 while staging) ---
    gemm_mfma_kernel<N_IN, N_H, 128, 1, true, false, false, _Float16>
        <<<dim3(N_H / 128, mt), TB, 0, stream>>>(
        x, w1T, b1, T16a, N, sums, nullptr, nullptr, nullptr, nullptr, nullptr);
    finalize_stats_kernel<<<1, N_H, 0, stream>>>(sums, g1, be1, ab, 1.0f / N);
    // --- layer 2: stage x0 = gelu(bn1(T1)) (x0 -> Ah0 from col-block 0), T2 = x0 @ w2 + b2 ---
    gemm_mfma_kernel<N_H, N_H, 128, 2, true, true, false, _Float16>
        <<<dim3(N_H / 128, mt), TB, 0, stream>>>(
        T16a, w2T, b2, T16b, N, sums, ab, nullptr, Ah0, nullptr, nullptr);
    finalize_stats_kernel<<<1, N_H, 0, stream>>>(sums, g2, be2, ab, 1.0f / N);
    // --- layer 3: stage x1 = gelu(bn2(T2)+x0) (x1 -> Ah1), T3 = x1 @ w3 + b3 ---
    gemm_mfma_kernel<N_H, N_H, 128, 3, true, true, false, _Float16>
        <<<dim3(N_H / 128, mt), TB, 0, stream>>>(
        T16b, w3T, b3, T16a, N, sums, ab, Ah0, Ah1, nullptr, nullptr);
    finalize_stats_kernel<<<1, N_H, 0, stream>>>(sums, g3, be3, ab, 1.0f / N);
    // --- layer 4: stage x2 = gelu(bn3(T3)+x1) (not materialized), h = x2 @ w4 + b4 (f32),
    //     plus z0 = dinv .* h (f16) ---
    gemm_mfma_kernel<N_H, N_OUT, 64, 3, false, false, true, float>
        <<<dim3(1, mt), TB, 0, stream>>>(
        T16a, w4T, b4, hbuf, N, nullptr, ab, Ah1, nullptr, dinv, z0);

    // --- propagation: z_k = D^{-1} A z_{k-1}, column-tiled (L2-resident gathers) ---
    int nbProp = (N + 15) / 16;
    for (int k = 1; k <= KHOP; ++k) {
        prop_tile_kernel<0><<<nbProp, 1024, 0, stream>>>(
            zk[k - 1], zpart, nullptr, colv, rp4, dinv2, N, 0);
        for (int t = 1; t < NT - 1; ++t)
            prop_tile_kernel<1><<<nbProp, 1024, 0, stream>>>(
                zk[k - 1], zpart, nullptr, colv, rp4, dinv2, N, t);
        prop_tile_kernel<2><<<nbProp, 1024, 0, stream>>>(
            zk[k - 1], zpart, zk[k], colv, rp4, dinv2, N, NT - 1);
    }

    // --- final accumulation ---
    ZPtrs zp;
    for (int k = 0; k < KHOP; ++k) zp.p[k] = zk[k + 1];
    int total4 = N * N_OUT / 4;
    prop_final_kernel<<<(total4 + TB - 1) / TB, TB, 0, stream>>>(hbuf, zp, sqd, alpha, out, total4);
}

// Round 5
// 1532.199 us; speedup vs baseline: 1.6465x; 1.6465x over previous
//
#include <hip/hip_runtime.h>
#include <math.h>

#define N_NODES 100000
#define N_IN 512
#define N_H 256
#define N_OUT 64
#define KHOP 10
#define EPS_BN 1e-5f
#define INV_TEMP (1.0f/1.5f)
#define TILE_W 25000          // column-tile width used by the CSR segmenting (kept from R4)

using half8  = __attribute__((ext_vector_type(8))) _Float16;
using half4  = __attribute__((ext_vector_type(4))) _Float16;
using floatx4 = __attribute__((ext_vector_type(4))) float;

struct ZPtrs { const _Float16* p[KHOP]; };

// ---------------- CSR build (tiled: segments per (row, col-tile)) ----------------

__global__ void init_kernel(int* __restrict__ cnt4, float* __restrict__ sums, int n4) {
    int i = blockIdx.x * blockDim.x + threadIdx.x;
    if (i < n4) cnt4[i] = 0;
    if (i < 2 * N_H) sums[i] = 0.f;
}

// Pre-pass (grid union): edge-rank atomics (per (row,tile) segment) + weight transposes.
// NOTE: deliberately NO bulk streaming here — co-scheduling streams under the
// atomic-RMW wall contended (R1: 205us vs 128us atomic-only).
__global__ __launch_bounds__(256) void fused_pre_kernel(
    const int* __restrict__ ei, int* __restrict__ cnt4, unsigned short* __restrict__ pos,
    const float* __restrict__ w1, _Float16* __restrict__ w1T,
    const float* __restrict__ w2, _Float16* __restrict__ w2T,
    const float* __restrict__ w3, _Float16* __restrict__ w3T,
    const float* __restrict__ w4, _Float16* __restrict__ w4T,
    int E, int nbE) {
    int bid = blockIdx.x;
    int t = threadIdx.x;
    if (bid < nbE) {
        int i = bid * 256 + t;
        if (i < E) {
            int r = ei[i];
            int c = ei[E + i];
            pos[i] = (unsigned short)atomicAdd(&cnt4[(r << 2) + c / TILE_W], 1);
        }
        return;
    }
    bid -= nbE;
    if (bid < 512) {            // w1: [512][256] -> w1T[n*512+k]
        int i = bid * 256 + t;
        int k = i >> 8, n = i & 255;
        w1T[(size_t)n * 512 + k] = (_Float16)w1[i];
        return;
    }
    bid -= 512;
    if (bid < 256) {            // w2: [256][256]
        int i = bid * 256 + t;
        int k = i >> 8, n = i & 255;
        w2T[(size_t)n * 256 + k] = (_Float16)w2[i];
        return;
    }
    bid -= 256;
    if (bid < 256) {            // w3: [256][256]
        int i = bid * 256 + t;
        int k = i >> 8, n = i & 255;
        w3T[(size_t)n * 256 + k] = (_Float16)w3[i];
        return;
    }
    bid -= 256;
    {                           // w4: [256][64]
        int i = bid * 256 + t;
        int k = i >> 6, n = i & 63;
        w4T[(size_t)n * 256 + k] = (_Float16)w4[i];
    }
}

// scan over 4N (row,tile) counts; self-loop (+1) added at tile (r / TILE_W).
// block = 256 threads x 4 elems = 1024 per block.
__global__ void scan1_kernel(const int* __restrict__ cnt4, int* __restrict__ excl,
                             int* __restrict__ bsum, int n4) {
    __shared__ int sd[256];
    int t = threadIdx.x;
    int base = blockIdx.x * 1024 + t * 4;
    int v0 = 0, v1 = 0, v2 = 0, v3 = 0;
    if (base + 0 < n4) { int g = base + 0; v0 = cnt4[g] + (((g & 3) == ((g >> 2) / TILE_W)) ? 1 : 0); }
    if (base + 1 < n4) { int g = base + 1; v1 = cnt4[g] + (((g & 3) == ((g >> 2) / TILE_W)) ? 1 : 0); }
    if (base + 2 < n4) { int g = base + 2; v2 = cnt4[g] + (((g & 3) == ((g >> 2) / TILE_W)) ? 1 : 0); }
    if (base + 3 < n4) { int g = base + 3; v3 = cnt4[g] + (((g & 3) == ((g >> 2) / TILE_W)) ? 1 : 0); }
    int tot = v0 + v1 + v2 + v3;
    sd[t] = tot;
    __syncthreads();
    for (int off = 1; off < 256; off <<= 1) {
        int x = (t >= off) ? sd[t - off] : 0;
        __syncthreads();
        sd[t] += x;
        __syncthreads();
    }
    int run = sd[t] - tot;   // exclusive
    if (t == 255) bsum[blockIdx.x] = sd[t];
    if (base + 0 < n4) excl[base + 0] = run; run += v0;
    if (base + 1 < n4) excl[base + 1] = run; run += v1;
    if (base + 2 < n4) excl[base + 2] = run; run += v2;
    if (base + 3 < n4) excl[base + 3] = run;
}

__global__ void scan2_kernel(int* __restrict__ bsum, int nb) {
    __shared__ int sd[512];
    int t = threadIdx.x;
    int v = (t < nb) ? bsum[t] : 0;
    sd[t] = v;
    __syncthreads();
    for (int off = 1; off < 512; off <<= 1) {
        int x = (t >= off) ? sd[t - off] : 0;
        __syncthreads();
        sd[t] += x;
        __syncthreads();
    }
    if (t < nb) bsum[t] = sd[t] - v;   // exclusive
}

// finalize rp4, per-node scalars, and write self-loop columns (at end of own tile segment).
__global__ void scan3_kernel(int* __restrict__ rp4, const int* __restrict__ bsum,
                             const int* __restrict__ cnt4, float* __restrict__ dinv,
                             float* __restrict__ dinv2, float* __restrict__ sqd,
                             int* __restrict__ colv, int n4, int total) {
    int g = blockIdx.x * blockDim.x + threadIdx.x;
    if (g < n4) {
        int rpf = rp4[g] + bsum[g >> 10];
        rp4[g] = rpf;
        int r = g >> 2, t = g & 3;
        int cv = cnt4[g];
        if (t == r / TILE_W) colv[rpf + cv] = r;   // self loop slot
        if (t == 0) {
            int4 c4 = *reinterpret_cast<const int4*>(&cnt4[g]);
            float d = (float)(c4.x + c4.y + c4.z + c4.w + 1);
            dinv[r]  = rsqrtf(d);
            dinv2[r] = 1.0f / d;
            sqd[r]   = sqrtf(d);
        }
    }
    if (g == 0) rp4[n4] = total;
}

// bucketed fill, NO atomics: slot from pos[] (rank within (row,tile) segment).
// Only rows in [r0, r1) handled per pass -> scatter window ~3.4 MB (L2-resident).
__global__ void fill_kernel(const int* __restrict__ ei, const unsigned short* __restrict__ pos,
                            const int* __restrict__ rp4,
                            int* __restrict__ colv, int E, int r0, int r1) {
    int i = blockIdx.x * blockDim.x + threadIdx.x;
    if (i >= E) return;
    int r = ei[i];
    if (r < r0 || r >= r1) return;
    int c = ei[E + i];
    colv[rp4[(r << 2) + c / TILE_W] + pos[i]] = c;
}

// ---------------- MFMA GEMM: C = A * BT^T + bias, fused A-prologue, reg-dbuf ----------------
// BM=128, BN in {128, 64}. 256 threads = 4 waves in 2x2; each wave 4 x WTN tiles of
// 16x16, MFMA 16x16x32 f16.  (R2 lesson: BN=256 caps occupancy -> latency-bound.)
// REG-DBUF (R5): next K-step's raw global loads are issued right after the current
// LDS-write phase, BEFORE the barrier — in flight across barrier+MFMA, consumed at the
// next iteration's convert phase.  Hides HBM latency at low occupancy.
// AMODE: 0 = A f16; 1 = A f32 (convert at stage); 2 = f16 pre-BN (ab+GELU at stage);
//        3 = like 2 plus residual from res[].
// WRITE_X (blockIdx.x==0 only): store staged activation for later residual use.
// STATS: fused column sum/sumsq.  WRITE_Z: z0 = dinv[row]*C (f16).
// LDS stride 40 halves (80B): frag ds_read_b128 bank-chunk = (5m+q) mod 8 -> conflict-free.

#define GELU(u) (0.5f * (u) * (1.f + erff((u) * 0.70710678118654752f)))

template<int KDIM, int NDIM, int BN, int AMODE, bool STATS, bool WRITE_X, bool WRITE_Z, typename CT>
__global__ __launch_bounds__(256) void gemm_mfma_kernel(
    const void* __restrict__ Araw, const _Float16* __restrict__ BT,
    const float* __restrict__ bias, CT* __restrict__ C, int M,
    float* __restrict__ sums, const float* __restrict__ ab,
    const _Float16* __restrict__ res, _Float16* __restrict__ xout,
    const float* __restrict__ dinv, _Float16* __restrict__ z0) {
    constexpr int BM = 128;
    constexpr int LDK = 40;
    constexpr int WTN = BN / 32;
    constexpr int NB = BN / 64;
    __shared__ _Float16 As[BM * LDK];
    __shared__ _Float16 Bs[BN * LDK];
    __shared__ float cs[BN];
    __shared__ float cq[BN];
    int t = threadIdx.x;
    int mbase = blockIdx.y * BM;
    int nbase = blockIdx.x * BN;
    int wv = t >> 6, lane = t & 63;
    int wm = (wv & 1) * 64;
    int wn = (wv >> 1) * (BN / 2);
    int q = lane >> 4;        // quad
    int fr = lane & 15;
    int sr = t >> 2;          // staging row 0..63
    int sc = (t & 3) * 8;     // staging k-offset (halves)
    bool xwrite = WRITE_X && (blockIdx.x == 0);
    bool mok[2] = { mbase + sr < M, mbase + sr + 64 < M };

    floatx4 acc[4][WTN];
    for (int mt = 0; mt < 4; ++mt)
        for (int nt = 0; nt < WTN; ++nt)
            acc[mt][nt] = floatx4{0.f, 0.f, 0.f, 0.f};

    // raw staging registers
    half8  aH[2];
    float4 aF[2][2];
    half8  rH[2];
    half8  bR[NB];

    auto issue_loads = [&](int kc) {
        #pragma unroll
        for (int p = 0; p < 2; ++p) {
            int grow = mbase + sr + p * 64;
            if (mok[p]) {
                if constexpr (AMODE == 1) {
                    const float* Af = (const float*)Araw + (size_t)grow * KDIM + kc;
                    aF[p][0] = *reinterpret_cast<const float4*>(Af);
                    aF[p][1] = *reinterpret_cast<const float4*>(Af + 4);
                } else {
                    aH[p] = *reinterpret_cast<const half8*>(
                        &((const _Float16*)Araw)[(size_t)grow * KDIM + kc]);
                    if constexpr (AMODE == 3)
                        rH[p] = *reinterpret_cast<const half8*>(&res[(size_t)grow * KDIM + kc]);
                }
            }
        }
        #pragma unroll
        for (int p = 0; p < NB; ++p)
            bR[p] = *reinterpret_cast<const half8*>(
                &BT[(size_t)(nbase + sr + p * 64) * KDIM + kc]);
    };

    issue_loads(sc);

    for (int k0 = 0; k0 < KDIM; k0 += 32) {
        int kc = k0 + sc;
        // --- convert current raw -> LDS ---
        #pragma unroll
        for (int p = 0; p < 2; ++p) {
            int row = sr + p * 64;
            int grow = mbase + row;
            half8 v = {};
            if (mok[p]) {
                if constexpr (AMODE == 0) {
                    v = aH[p];
                } else if constexpr (AMODE == 1) {
                    v[0] = (_Float16)aF[p][0].x; v[1] = (_Float16)aF[p][0].y;
                    v[2] = (_Float16)aF[p][0].z; v[3] = (_Float16)aF[p][0].w;
                    v[4] = (_Float16)aF[p][1].x; v[5] = (_Float16)aF[p][1].y;
                    v[6] = (_Float16)aF[p][1].z; v[7] = (_Float16)aF[p][1].w;
                } else {
                    float4 a0 = *reinterpret_cast<const float4*>(&ab[kc]);
                    float4 a1 = *reinterpret_cast<const float4*>(&ab[kc + 4]);
                    float4 b0 = *reinterpret_cast<const float4*>(&ab[KDIM + kc]);
                    float4 b1 = *reinterpret_cast<const float4*>(&ab[KDIM + kc + 4]);
                    float u[8];
                    u[0] = a0.x * (float)aH[p][0] + b0.x;
                    u[1] = a0.y * (float)aH[p][1] + b0.y;
                    u[2] = a0.z * (float)aH[p][2] + b0.z;
                    u[3] = a0.w * (float)aH[p][3] + b0.w;
                    u[4] = a1.x * (float)aH[p][4] + b1.x;
                    u[5] = a1.y * (float)aH[p][5] + b1.y;
                    u[6] = a1.z * (float)aH[p][6] + b1.z;
                    u[7] = a1.w * (float)aH[p][7] + b1.w;
                    if constexpr (AMODE == 3) {
                        #pragma unroll
                        for (int j = 0; j < 8; ++j) u[j] += (float)rH[p][j];
                    }
                    #pragma unroll
                    for (int j = 0; j < 8; ++j) v[j] = (_Float16)GELU(u[j]);
                    if (xwrite)
                        *reinterpret_cast<half8*>(&xout[(size_t)grow * KDIM + kc]) = v;
                }
            }
            *reinterpret_cast<half8*>(&As[row * LDK + sc]) = v;
        }
        #pragma unroll
        for (int p = 0; p < NB; ++p)
            *reinterpret_cast<half8*>(&Bs[(sr + p * 64) * LDK + sc]) = bR[p];
        // --- issue next K-step loads (in flight across barrier + MFMA) ---
        if (k0 + 32 < KDIM) issue_loads(kc + 32);
        __syncthreads();
        half8 af[4], bf[WTN];
        #pragma unroll
        for (int mt = 0; mt < 4; ++mt)
            af[mt] = *reinterpret_cast<const half8*>(&As[(wm + mt * 16 + fr) * LDK + q * 8]);
        #pragma unroll
        for (int nt = 0; nt < WTN; ++nt)
            bf[nt] = *reinterpret_cast<const half8*>(&Bs[(wn + nt * 16 + fr) * LDK + q * 8]);
        #pragma unroll
        for (int mt = 0; mt < 4; ++mt)
            #pragma unroll
            for (int nt = 0; nt < WTN; ++nt)
                acc[mt][nt] = __builtin_amdgcn_mfma_f32_16x16x32_f16(af[mt], bf[nt], acc[mt][nt], 0, 0, 0);
        __syncthreads();
    }
    if constexpr (STATS) {
        if (t < BN) { cs[t] = 0.f; cq[t] = 0.f; }
        __syncthreads();
    }
    // epilogue: D layout col = lane&15, row = (lane>>4)*4 + r
    #pragma unroll
    for (int nt = 0; nt < WTN; ++nt) {
        int col = nbase + wn + nt * 16 + fr;
        float bv = bias[col];
        float s = 0.f, s2 = 0.f;
        #pragma unroll
        for (int mt = 0; mt < 4; ++mt) {
            #pragma unroll
            for (int rr = 0; rr < 4; ++rr) {
                int row = mbase + wm + mt * 16 + q * 4 + rr;
                if (row < M) {
                    float v = acc[mt][nt][rr] + bv;
                    C[(size_t)row * NDIM + col] = (CT)v;
                    if constexpr (STATS) { s += v; s2 += v * v; }
                    if constexpr (WRITE_Z)
                        z0[((size_t)row << 6) + col] = (_Float16)(dinv[row] * v);
                }
            }
        }
        if constexpr (STATS) {
            s  += __shfl_xor(s, 16);  s  += __shfl_xor(s, 32);
            s2 += __shfl_xor(s2, 16); s2 += __shfl_xor(s2, 32);
            if (q == 0) {
                atomicAdd(&cs[wn + nt * 16 + fr], s);
                atomicAdd(&cq[wn + nt * 16 + fr], s2);
            }
        }
    }
    if constexpr (STATS) {
        __syncthreads();
        if (t < BN) {
            atomicAdd(&sums[nbase + t], cs[t]);
            atomicAdd(&sums[N_H + nbase + t], cq[t]);
        }
    }
}

// ---------------- BatchNorm finalize (also re-zeroes sums for the next layer) ----------------

__global__ void finalize_stats_kernel(float* __restrict__ sums,
                                      const float* __restrict__ g, const float* __restrict__ be,
                                      float* __restrict__ ab, float invM) {
    int c = threadIdx.x;
    float s = sums[c], s2 = sums[N_H + c];
    float mean = s * invM;
    float var = s2 * invM - mean * mean;
    float a = g[c] * rsqrtf(var + EPS_BN);
    ab[c] = a;
    ab[N_H + c] = be[c] - mean * a;
    sums[c] = 0.f;
    sums[N_H + c] = 0.f;
}

// ---------------- Propagation (single-pass per hop; R4 tiling reverted) ----------------
// z_k[r] = (1/deg[r]) * sum_{c in N(r)} z_{k-1}[c].  One wave per row.  Full-row range
// spans the 4 contiguous tile segments: [rp4[r*4], rp4[r*4+4]).
// R5: 32-edge main loop — 8 colv + 8 z-gathers in flight per wave (2x the MLP of R3's
// 16-edge loop) to test/exploit the latency-bound regime.

__global__ __launch_bounds__(256) void prop_kernel(
    const _Float16* __restrict__ zin, _Float16* __restrict__ zout,
    const int* __restrict__ colv, const int* __restrict__ rp4,
    const float* __restrict__ dinv2, int n) {
    int r = (blockIdx.x << 2) + (threadIdx.x >> 6);
    if (r >= n) return;
    int lane = threadIdx.x & 63;
    int esub = lane >> 4;       // 0..3
    int fo = (lane & 15) << 2;  // feature offset 0..60
    int s = __builtin_amdgcn_readfirstlane(rp4[r << 2]);
    int e = __builtin_amdgcn_readfirstlane(rp4[(r << 2) + 4]);
    float a0 = 0.f, a1 = 0.f, a2 = 0.f, a3 = 0.f;
    int i = s;
    for (; i + 32 <= e; i += 32) {
        int cc[8]; half4 vv[8];
        #pragma unroll
        for (int j = 0; j < 8; ++j) cc[j] = colv[i + 4 * j + esub];
        #pragma unroll
        for (int j = 0; j < 8; ++j)
            vv[j] = *reinterpret_cast<const half4*>(&zin[((size_t)cc[j] << 6) + fo]);
        #pragma unroll
        for (int j = 0; j < 8; ++j) {
            a0 += (float)vv[j].x; a1 += (float)vv[j].y;
            a2 += (float)vv[j].z; a3 += (float)vv[j].w;
        }
    }
    for (; i + 16 <= e; i += 16) {
        int cc[4]; half4 vv[4];
        #pragma unroll
        for (int j = 0; j < 4; ++j) cc[j] = colv[i + 4 * j + esub];
        #pragma unroll
        for (int j = 0; j < 4; ++j)
            vv[j] = *reinterpret_cast<const half4*>(&zin[((size_t)cc[j] << 6) + fo]);
        #pragma unroll
        for (int j = 0; j < 4; ++j) {
            a0 += (float)vv[j].x; a1 += (float)vv[j].y;
            a2 += (float)vv[j].z; a3 += (float)vv[j].w;
        }
    }
    for (; i + 4 <= e; i += 4) {
        int c = colv[i + esub];
        half4 v = *reinterpret_cast<const half4*>(&zin[((size_t)c << 6) + fo]);
        a0 += (float)v.x; a1 += (float)v.y; a2 += (float)v.z; a3 += (float)v.w;
    }
    if (esub < e - i) {
        int c = colv[i + esub];
        half4 v = *reinterpret_cast<const half4*>(&zin[((size_t)c << 6) + fo]);
        a0 += (float)v.x; a1 += (float)v.y; a2 += (float)v.z; a3 += (float)v.w;
    }
    a0 += __shfl_xor(a0, 16); a1 += __shfl_xor(a1, 16);
    a2 += __shfl_xor(a2, 16); a3 += __shfl_xor(a3, 16);
    a0 += __shfl_xor(a0, 32); a1 += __shfl_xor(a1, 32);
    a2 += __shfl_xor(a2, 32); a3 += __shfl_xor(a3, 32);
    if (lane < 16) {
        float d = dinv2[r];
        half4 o;
        o.x = (_Float16)(a0 * d); o.y = (_Float16)(a1 * d);
        o.z = (_Float16)(a2 * d); o.w = (_Float16)(a3 * d);
        *reinterpret_cast<half4*>(&zout[((size_t)r << 6) + fo]) = o;
    }
}

// out = INV_TEMP * (alpha0 * h + sqrt(deg[r]) * sum_k alpha_k * z_k)
__global__ void prop_final_kernel(const float* __restrict__ h, ZPtrs zp,
                                  const float* __restrict__ sqd,
                                  const float* __restrict__ alpha,
                                  float* __restrict__ out, int total4) {
    int i = blockIdx.x * blockDim.x + threadIdx.x;
    if (i >= total4) return;
    int r = i >> 4;                       // (i*4)/64
    float4 hv = reinterpret_cast<const float4*>(h)[i];
    float s0 = 0.f, s1 = 0.f, s2 = 0.f, s3 = 0.f;
    #pragma unroll
    for (int k = 0; k < KHOP; ++k) {
        half4 z = reinterpret_cast<const half4*>(zp.p[k])[i];
        float ak = alpha[k + 1];
        s0 += ak * (float)z.x; s1 += ak * (float)z.y;
        s2 += ak * (float)z.z; s3 += ak * (float)z.w;
    }
    float sq = sqd[r];
    float a0 = alpha[0];
    float4 o;
    o.x = INV_TEMP * (a0 * hv.x + sq * s0);
    o.y = INV_TEMP * (a0 * hv.y + sq * s1);
    o.z = INV_TEMP * (a0 * hv.z + sq * s2);
    o.w = INV_TEMP * (a0 * hv.w + sq * s3);
    reinterpret_cast<float4*>(out)[i] = o;
}

// ---------------- Host ----------------

extern "C" void kernel_launch(void* const* d_in, const int* in_sizes, int n_in,
                              void* d_out, int out_size, void* d_ws, size_t ws_size,
                              hipStream_t stream) {
    const float* x    = (const float*)d_in[0];
    const int*   ei   = (const int*)d_in[1];
    const float* w1   = (const float*)d_in[2];
    const float* b1   = (const float*)d_in[3];
    const float* g1   = (const float*)d_in[4];
    const float* be1  = (const float*)d_in[5];
    const float* w2   = (const float*)d_in[6];
    const float* b2   = (const float*)d_in[7];
    const float* g2   = (const float*)d_in[8];
    const float* be2  = (const float*)d_in[9];
    const float* w3   = (const float*)d_in[10];
    const float* b3   = (const float*)d_in[11];
    const float* g3   = (const float*)d_in[12];
    const float* be3  = (const float*)d_in[13];
    const float* w4   = (const float*)d_in[14];
    const float* b4   = (const float*)d_in[15];
    const float* alpha= (const float*)d_in[16];
    float* out = (float*)d_out;

    const int N = in_sizes[0] / N_IN;     // 100000
    const int E = in_sizes[1] / 2;        // 3200000
    const int EN = E + N;
    const int N4 = N * 4;
    const size_t NZ = (size_t)N * N_OUT;  // elements per z buffer

    char* ws = (char*)d_ws;
    size_t off = 0;
    auto alloc = [&](size_t bytes) -> void* {
        void* p = ws + off;
        off = (off + bytes + 255) & ~(size_t)255;
        return p;
    };
    int*   cnt4    = (int*)alloc((size_t)N4 * 4);         // per (row,tile) raw edge counts
    int*   rp4     = (int*)alloc((size_t)(N4 + 1) * 4);   // segment ptrs, row-major (r,t)
    float* dinv    = (float*)alloc((size_t)N * 4);
    float* dinv2   = (float*)alloc((size_t)N * 4);
    float* sqd     = (float*)alloc((size_t)N * 4);
    int*   colv    = (int*)alloc((size_t)EN * 4);
    unsigned short* pos = (unsigned short*)alloc((size_t)E * 2);
    int*   bsum    = (int*)alloc(512 * 4);
    float* sums    = (float*)alloc(2 * N_H * 4);
    float* ab      = (float*)alloc(2 * N_H * 4);
    _Float16* w1T  = (_Float16*)alloc((size_t)N_IN * N_H * 2);
    _Float16* w2T  = (_Float16*)alloc((size_t)N_H * N_H * 2);
    _Float16* w3T  = (_Float16*)alloc((size_t)N_H * N_H * 2);
    _Float16* w4T  = (_Float16*)alloc((size_t)N_H * N_OUT * 2);
    float* T       = (float*)alloc((size_t)N * N_H * 4);    // two f16 halves (ping-pong); reused as z1..z8
    _Float16* Ah0  = (_Float16*)alloc((size_t)N * N_H * 2); // x0
    _Float16* Ah1  = (_Float16*)alloc((size_t)N * N_H * 2); // x1; reused as z9,z10
    float* hbuf    = (float*)alloc((size_t)N * N_OUT * 4);
    _Float16* z0   = (_Float16*)alloc(NZ * 2);

    _Float16* T16a = (_Float16*)T;
    _Float16* T16b = (_Float16*)T + (size_t)N * N_H;

    // z-buffer ring: z1..z8 live in T region (8*12.8MB), z9,z10 in Ah1
    _Float16* zk[KHOP + 1];
    zk[0] = z0;
    for (int k = 1; k <= 8; ++k) zk[k] = (_Float16*)T + (size_t)(k - 1) * NZ;
    zk[9]  = (_Float16*)Ah1;
    zk[10] = (_Float16*)Ah1 + NZ;

    const int TB = 256;
    int nbN4 = (N4 + TB - 1) / TB;
    int nbE  = (E + TB - 1) / TB;
    int nscan = (N4 + 1023) / 1024;

    // --- pre-pass: (row,tile) edge-rank atomics + weight transposes ---
    init_kernel<<<nbN4, TB, 0, stream>>>(cnt4, sums, N4);
    {
        int grid = nbE + 512 + 256 + 256 + 64;
        fused_pre_kernel<<<grid, TB, 0, stream>>>(ei, cnt4, pos,
                                                  w1, w1T, w2, w2T, w3, w3T, w4, w4T,
                                                  E, nbE);
    }

    // --- CSR scan + finalize (self loops written in scan3) ---
    scan1_kernel<<<nscan, TB, 0, stream>>>(cnt4, rp4, bsum, N4);
    scan2_kernel<<<1, 512, 0, stream>>>(bsum, nscan);
    scan3_kernel<<<nbN4, TB, 0, stream>>>(rp4, bsum, cnt4, dinv, dinv2, sqd, colv, N4, EN);

    // --- atomic-free bucketed fill ---
    {
        const int P = 4;
        int step = (N + P - 1) / P;
        for (int p = 0; p < P; ++p) {
            int r0 = p * step;
            int r1 = min(N, r0 + step);
            fill_kernel<<<nbE, TB, 0, stream>>>(ei, pos, rp4, colv, E, r0, r1);
        }
    }

    int mt = (N + 127) / 128;

    // --- layer 1: T1 = x(f32) @ w1 + b1 (A converted to f16 while staging) ---
    gemm_mfma_kernel<N_IN, N_H, 128, 1, true, false, false, _Float16>
        <<<dim3(N_H / 128, mt), TB, 0, stream>>>(
        x, w1T, b1, T16a, N, sums, nullptr, nullptr, nullptr, nullptr, nullptr);
    finalize_stats_kernel<<<1, N_H, 0, stream>>>(sums, g1, be1, ab, 1.0f / N);
    // --- layer 2: stage x0 = gelu(bn1(T1)) (x0 -> Ah0 from col-block 0), T2 = x0 @ w2 + b2 ---
    gemm_mfma_kernel<N_H, N_H, 128, 2, true, true, false, _Float16>
        <<<dim3(N_H / 128, mt), TB, 0, stream>>>(
        T16a, w2T, b2, T16b, N, sums, ab, nullptr, Ah0, nullptr, nullptr);
    finalize_stats_kernel<<<1, N_H, 0, stream>>>(sums, g2, be2, ab, 1.0f / N);
    // --- layer 3: stage x1 = gelu(bn2(T2)+x0) (x1 -> Ah1), T3 = x1 @ w3 + b3 ---
    gemm_mfma_kernel<N_H, N_H, 128, 3, true, true, false, _Float16>
        <<<dim3(N_H / 128, mt), TB, 0, stream>>>(
        T16b, w3T, b3, T16a, N, sums, ab, Ah0, Ah1, nullptr, nullptr);
    finalize_stats_kernel<<<1, N_H, 0, stream>>>(sums, g3, be3, ab, 1.0f / N);
    // --- layer 4: stage x2 = gelu(bn3(T3)+x1) (not materialized), h = x2 @ w4 + b4 (f32),
    //     plus z0 = dinv .* h (f16) ---
    gemm_mfma_kernel<N_H, N_OUT, 64, 3, false, false, true, float>
        <<<dim3(1, mt), TB, 0, stream>>>(
        T16a, w4T, b4, hbuf, N, nullptr, ab, Ah1, nullptr, dinv, z0);

    // --- propagation: z_k = D^{-1} A z_{k-1} ---
    int nbProp = (N + 3) / 4;
    for (int k = 1; k <= KHOP; ++k) {
        prop_kernel<<<nbProp, TB, 0, stream>>>(zk[k - 1], zk[k], colv, rp4, dinv2, N);
    }

    // --- final accumulation ---
    ZPtrs zp;
    for (int k = 0; k < KHOP; ++k) zp.p[k] = zk[k + 1];
    int total4 = N * N_OUT / 4;
    prop_final_kernel<<<(total4 + TB - 1) / TB, TB, 0, stream>>>(hbuf, zp, sqd, alpha, out, total4);
}